// Round 2
// baseline (1355.508 us; speedup 1.0000x reference)
//
#include <hip/hip_runtime.h>
#include <math.h>

#define LD    512      // latent dim
#define CB    1024     // codebook size
#define NTOK  65536    // 16*4096 tokens

// a2/b2 scratch lives in the *quantized* region of d_out (NTOK*LD floats).
// K1 writes it, K2 reads it, K3 fully overwrites the region with the real
// output. No d_ws usage anywhere (ws_size may be tiny).

// ---------------------------------------------------------------------------
// K1: row sum-of-squares for x (NTOK rows) and codebook (CB rows).
// One wave per row; lane reads 2 float4s (128 float4 per row / 64 lanes).
// ---------------------------------------------------------------------------
__global__ __launch_bounds__(256)
void sumsq_kernel(const float* __restrict__ x,
                  const float* __restrict__ cb,
                  float* __restrict__ a2,
                  float* __restrict__ b2) {
    int wave = (int)((blockIdx.x * blockDim.x + threadIdx.x) >> 6);
    int lane = threadIdx.x & 63;
    const float* src;
    float* dst;
    int row;
    if (wave < NTOK) { src = x;  dst = a2; row = wave; }
    else             { src = cb; dst = b2; row = wave - NTOK; if (row >= CB) return; }
    const float4* p = (const float4*)(src + (size_t)row * LD);
    float4 v0 = p[lane];
    float4 v1 = p[lane + 64];
    float s = v0.x*v0.x + v0.y*v0.y + v0.z*v0.z + v0.w*v0.w
            + v1.x*v1.x + v1.y*v1.y + v1.z*v1.z + v1.w*v1.w;
    #pragma unroll
    for (int off = 32; off > 0; off >>= 1) s += __shfl_down(s, off, 64);
    if (lane == 0) dst[row] = s;
}

// ---------------------------------------------------------------------------
// K2: fp32 tiled GEMM: dist[m][n] = a2[m] - 2*dot(x[m], cb[n]) + b2[n]
// BM=BN=64, BK=32, 256 threads, 4x4 microtile per thread.
// LDS tiles stored transposed (k-major) with padded leading dim 68 so the
// inner loop does 2x ds_read_b128 + 16 v_fma per k.
// ---------------------------------------------------------------------------
#define BM 64
#define BN 64
#define BK 32
#define LDT 68   // padded leading dim (floats); keeps float4 alignment

__global__ __launch_bounds__(256)
void dist_gemm_kernel(const float* __restrict__ x,
                      const float* __restrict__ cb,
                      const float* __restrict__ a2,
                      const float* __restrict__ b2,
                      float* __restrict__ dist) {
    __shared__ float As[BK][LDT];   // As[k][token_in_tile]
    __shared__ float Bs[BK][LDT];   // Bs[k][code_in_tile]

    const int tid = threadIdx.x;
    const int tx  = tid & 15;       // code quad   (0..15)
    const int ty  = tid >> 4;       // token quad  (0..15)
    const int m0  = blockIdx.y * BM;
    const int n0  = blockIdx.x * BN;

    // staging: thread t covers row t/4, k-offset (t%4)*4, two passes of 16 k.
    const int lr = tid >> 2;
    const int lk = (tid & 3) * 4;

    float acc[4][4] = {};

    for (int k0 = 0; k0 < LD; k0 += BK) {
        #pragma unroll
        for (int pass = 0; pass < 2; ++pass) {
            const int kk = lk + pass * 16;
            float4 av = *(const float4*)(x  + (size_t)(m0 + lr) * LD + k0 + kk);
            float4 bv = *(const float4*)(cb + (size_t)(n0 + lr) * LD + k0 + kk);
            As[kk+0][lr] = av.x; As[kk+1][lr] = av.y;
            As[kk+2][lr] = av.z; As[kk+3][lr] = av.w;
            Bs[kk+0][lr] = bv.x; Bs[kk+1][lr] = bv.y;
            Bs[kk+2][lr] = bv.z; Bs[kk+3][lr] = bv.w;
        }
        __syncthreads();
        #pragma unroll
        for (int k = 0; k < BK; ++k) {
            float4 a4 = *(const float4*)&As[k][ty * 4];
            float4 b4 = *(const float4*)&Bs[k][tx * 4];
            float a[4] = {a4.x, a4.y, a4.z, a4.w};
            float b[4] = {b4.x, b4.y, b4.z, b4.w};
            #pragma unroll
            for (int i = 0; i < 4; ++i)
                #pragma unroll
                for (int j = 0; j < 4; ++j)
                    acc[i][j] += a[i] * b[j];
        }
        __syncthreads();
    }

    // epilogue: dist = a2 - 2*dot + b2
    float b2v[4];
    #pragma unroll
    for (int j = 0; j < 4; ++j) b2v[j] = b2[n0 + tx * 4 + j];
    #pragma unroll
    for (int i = 0; i < 4; ++i) {
        const int m = m0 + ty * 4 + i;
        const float a2v = a2[m];
        float4 o;
        o.x = a2v - 2.f * acc[i][0] + b2v[0];
        o.y = a2v - 2.f * acc[i][1] + b2v[1];
        o.z = a2v - 2.f * acc[i][2] + b2v[2];
        o.w = a2v - 2.f * acc[i][3] + b2v[3];
        *(float4*)(dist + (size_t)m * CB + n0 + tx * 4) = o;
    }
}

// ---------------------------------------------------------------------------
// K3: per-token argmin over 1024 distances (np.argmin first-min tie-break)
// + gather quantized = codebook[argmin]. One wave per token.
// In-lane indices ascend so strict < keeps the first occurrence; cross-lane
// ties take the smaller global index.
// ---------------------------------------------------------------------------
__global__ __launch_bounds__(256)
void argmin_gather_kernel(const float* __restrict__ dist,
                          const float* __restrict__ cb,
                          float* __restrict__ quant) {
    int wave = (int)((blockIdx.x * blockDim.x + threadIdx.x) >> 6);
    int lane = threadIdx.x & 63;
    if (wave >= NTOK) return;

    const float4* dp = (const float4*)(dist + (size_t)wave * CB);
    float best = INFINITY;
    int bidx = 0x7fffffff;
    #pragma unroll
    for (int i = 0; i < 4; ++i) {
        float4 v = dp[i * 64 + lane];
        int base = (i * 64 + lane) * 4;
        if (v.x < best) { best = v.x; bidx = base + 0; }
        if (v.y < best) { best = v.y; bidx = base + 1; }
        if (v.z < best) { best = v.z; bidx = base + 2; }
        if (v.w < best) { best = v.w; bidx = base + 3; }
    }
    #pragma unroll
    for (int off = 32; off > 0; off >>= 1) {
        float ov = __shfl_down(best, off, 64);
        int   oi = __shfl_down(bidx, off, 64);
        if (ov < best || (ov == best && oi < bidx)) { best = ov; bidx = oi; }
    }
    bidx = __shfl(bidx, 0, 64);

    const float4* cp = (const float4*)(cb + (size_t)bidx * LD);
    float4* qp = (float4*)(quant + (size_t)wave * LD);
    qp[lane]      = cp[lane];
    qp[lane + 64] = cp[lane + 64];
}

// ---------------------------------------------------------------------------
extern "C" void kernel_launch(void* const* d_in, const int* in_sizes, int n_in,
                              void* d_out, int out_size, void* d_ws, size_t ws_size,
                              hipStream_t stream) {
    const float* x   = (const float*)d_in[0];   // 16*4096*512
    const float* cb  = (const float*)d_in[1];   // 1024*512
    float* quant = (float*)d_out;                       // NTOK*LD
    float* dist  = (float*)d_out + (size_t)NTOK * LD;   // NTOK*CB

    // a2/b2 scratch inside the quant region (fully overwritten by K3 later).
    float* a2 = quant;            // NTOK floats
    float* b2 = quant + NTOK;     // CB floats   (66,560 << NTOK*LD)

    // K1: sum-of-squares rows. (NTOK + CB) waves, 4 waves per block.
    {
        int waves = NTOK + CB;
        int blocks = (waves + 3) / 4;
        sumsq_kernel<<<blocks, 256, 0, stream>>>(x, cb, a2, b2);
    }
    // K2: distance GEMM.
    {
        dim3 grid(CB / BN, NTOK / BM);
        dist_gemm_kernel<<<grid, 256, 0, stream>>>(x, cb, a2, b2, dist);
    }
    // K3: argmin + gather (overwrites the a2/b2 scratch with real output).
    {
        int blocks = NTOK / 4;
        argmin_gather_kernel<<<blocks, 256, 0, stream>>>(dist, cb, quant);
    }
}

// Round 3
// 804.774 us; speedup vs baseline: 1.6843x; 1.6843x over previous
//
#include <hip/hip_runtime.h>
#include <math.h>

#define LD    512
#define CB    1024
#define NTOK  65536
#define HALFM 32768

typedef unsigned short u16;
typedef __attribute__((ext_vector_type(8))) short bf16x8;   // 8 bf16 (4 VGPRs)
typedef __attribute__((ext_vector_type(4))) float f32x4;

#define GLAS  __attribute__((address_space(1)))
#define LDSAS __attribute__((address_space(3)))

__device__ inline void glds16(const void* g, void* l) {
    __builtin_amdgcn_global_load_lds((const GLAS unsigned int*)g,
                                     (LDSAS unsigned int*)l, 16, 0, 0);
}

__device__ inline u16 f2bf_rne(float f) {
    union { float f; unsigned u; } v; v.f = f;
    unsigned u = v.u;
    return (u16)((u + 0x7fffu + ((u >> 16) & 1u)) >> 16);
}
__device__ inline float bf2f(u16 h) {
    union { unsigned u; float f; } v; v.u = ((unsigned)h) << 16;
    return v.f;
}

// ---------------------------------------------------------------------------
// Converter: per row (one wave): hi = bf16(x), lo = bf16(x - hi), sumsq(x).
// ---------------------------------------------------------------------------
__global__ __launch_bounds__(256)
void convert_rows_kernel(const float* __restrict__ src,
                         u16* __restrict__ hi,
                         u16* __restrict__ lo,
                         float* __restrict__ sumsq,
                         int nrows) {
    int wave = (int)((blockIdx.x * blockDim.x + threadIdx.x) >> 6);
    int lane = threadIdx.x & 63;
    if (wave >= nrows) return;
    const float4* p = (const float4*)(src + (size_t)wave * LD);
    float s = 0.f;
    #pragma unroll
    for (int c = 0; c < 2; ++c) {
        float4 v = p[lane + c * 64];
        float fs[4] = {v.x, v.y, v.z, v.w};
        ushort4 hv, lv;
        u16 hh[4], ll[4];
        #pragma unroll
        for (int e = 0; e < 4; ++e) {
            s += fs[e] * fs[e];
            u16 hb = f2bf_rne(fs[e]);
            float hf = bf2f(hb);
            hh[e] = hb;
            ll[e] = f2bf_rne(fs[e] - hf);
        }
        hv.x = hh[0]; hv.y = hh[1]; hv.z = hh[2]; hv.w = hh[3];
        lv.x = ll[0]; lv.y = ll[1]; lv.z = ll[2]; lv.w = ll[3];
        size_t off = (size_t)wave * LD + (size_t)(lane + c * 64) * 4;
        *(ushort4*)(hi + off) = hv;
        *(ushort4*)(lo + off) = lv;
    }
    #pragma unroll
    for (int off = 32; off > 0; off >>= 1) s += __shfl_down(s, off, 64);
    if (lane == 0) sumsq[wave] = s;
}

// ---------------------------------------------------------------------------
// MFMA distance GEMM: dist[m][n] = a2[m] - 2*(AhiBhi + AloBhi + AhiBlo) + b2[n]
// 128x128 tile, BK=64, 256 threads (4 waves, 2x2), 16x16x32 bf16 MFMA,
// 4x4 accumulators per wave, global_load_lds width-16 staging.
// ---------------------------------------------------------------------------
__global__ __launch_bounds__(256)
void mfma_dist_kernel(const u16* __restrict__ Ahi,
                      const u16* __restrict__ Alo,
                      const u16* __restrict__ Bhi,
                      const u16* __restrict__ Blo,
                      const float* __restrict__ a2,   // full array, index m_base+
                      const float* __restrict__ b2,
                      float* __restrict__ dist,       // full base, row stride CB
                      int m_base) {
    __shared__ u16 As[128 * 64];   // row-major: row m (128B), k contiguous
    __shared__ u16 Bs[128 * 64];

    const int tid  = threadIdx.x;
    const int lane = tid & 63;
    const int w    = tid >> 6;        // wave 0..3
    const int wm   = w >> 1;          // 2x2 wave grid
    const int wn   = w & 1;
    const int quad = lane >> 4;
    const int l15  = lane & 15;

    const int n0 = blockIdx.x * 128;
    const int m0 = blockIdx.y * 128;  // local (phase) row

    f32x4 acc[4][4];
    #pragma unroll
    for (int i = 0; i < 4; ++i)
        #pragma unroll
        for (int j = 0; j < 4; ++j) {
            f32x4 z = {0.f, 0.f, 0.f, 0.f};
            acc[i][j] = z;
        }

    const int scol = (lane & 7) * 8;  // element offset within 64-wide k chunk

    #pragma unroll 1
    for (int pass = 0; pass < 3; ++pass) {
        const u16* Ab = (pass == 1) ? Alo : Ahi;
        const u16* Bb = (pass == 2) ? Blo : Bhi;
        #pragma unroll 1
        for (int k0 = 0; k0 < LD; k0 += 64) {
            // stage 128x64 A and B tiles: 4 glds16 per wave per matrix
            #pragma unroll
            for (int t = 0; t < 4; ++t) {
                int r = w * 32 + t * 8 + (lane >> 3);
                const u16* ga = Ab + (size_t)(m0 + r) * LD + k0 + scol;
                const u16* gb = Bb + (size_t)(n0 + r) * LD + k0 + scol;
                u16* la = As + (w * 32 + t * 8) * 64;  // wave-uniform base
                u16* lb = Bs + (w * 32 + t * 8) * 64;
                glds16(ga, la);
                glds16(gb, lb);
            }
            __syncthreads();   // drains vmcnt (glds) before consume
            #pragma unroll
            for (int ks = 0; ks < 64; ks += 32) {
                bf16x8 af[4], bfr[4];
                #pragma unroll
                for (int i = 0; i < 4; ++i)
                    af[i] = *(const bf16x8*)&As[(wm * 64 + i * 16 + l15) * 64 + ks + quad * 8];
                #pragma unroll
                for (int j = 0; j < 4; ++j)
                    bfr[j] = *(const bf16x8*)&Bs[(wn * 64 + j * 16 + l15) * 64 + ks + quad * 8];
                #pragma unroll
                for (int i = 0; i < 4; ++i)
                    #pragma unroll
                    for (int j = 0; j < 4; ++j)
                        acc[i][j] = __builtin_amdgcn_mfma_f32_16x16x32_bf16(
                            af[i], bfr[j], acc[i][j], 0, 0, 0);
            }
            __syncthreads();   // protect LDS before next stage overwrite
        }
    }

    // epilogue: C/D layout col = lane&15, row = quad*4 + reg
    #pragma unroll
    for (int i = 0; i < 4; ++i) {
        float a2v[4];
        #pragma unroll
        for (int r = 0; r < 4; ++r)
            a2v[r] = a2[m_base + m0 + wm * 64 + i * 16 + quad * 4 + r];
        #pragma unroll
        for (int j = 0; j < 4; ++j) {
            int col = n0 + wn * 64 + j * 16 + l15;
            float b2v = b2[col];
            #pragma unroll
            for (int r = 0; r < 4; ++r) {
                int grow = m_base + m0 + wm * 64 + i * 16 + quad * 4 + r;
                dist[(size_t)grow * CB + col] = fmaf(-2.f, acc[i][j][r], a2v[r] + b2v);
            }
        }
    }
}

// ---------------------------------------------------------------------------
// K3: per-token argmin (np first-occurrence tie-break) + codebook gather.
// ---------------------------------------------------------------------------
__global__ __launch_bounds__(256)
void argmin_gather_kernel(const float* __restrict__ dist,
                          const float* __restrict__ cb,
                          float* __restrict__ quant) {
    int wave = (int)((blockIdx.x * blockDim.x + threadIdx.x) >> 6);
    int lane = threadIdx.x & 63;
    if (wave >= NTOK) return;

    const float4* dp = (const float4*)(dist + (size_t)wave * CB);
    float best = INFINITY;
    int bidx = 0x7fffffff;
    #pragma unroll
    for (int i = 0; i < 4; ++i) {
        float4 v = dp[i * 64 + lane];
        int base = (i * 64 + lane) * 4;
        if (v.x < best) { best = v.x; bidx = base + 0; }
        if (v.y < best) { best = v.y; bidx = base + 1; }
        if (v.z < best) { best = v.z; bidx = base + 2; }
        if (v.w < best) { best = v.w; bidx = base + 3; }
    }
    #pragma unroll
    for (int off = 32; off > 0; off >>= 1) {
        float ov = __shfl_down(best, off, 64);
        int   oi = __shfl_down(bidx, off, 64);
        if (ov < best || (ov == best && oi < bidx)) { best = ov; bidx = oi; }
    }
    bidx = __shfl(bidx, 0, 64);

    const float4* cp = (const float4*)(cb + (size_t)bidx * LD);
    float4* qp = (float4*)(quant + (size_t)wave * LD);
    qp[lane]      = cp[lane];
    qp[lane + 64] = cp[lane + 64];
}

// ---------------------------------------------------------------------------
// Memory plan inside d_out (no d_ws usage — ws_size proved too small in R1):
//   quant region Q   = d_out[0 .. 134,217,728)
//     cb_hi @0 (1MB), cb_lo @1MB, b2 @2MB (4KB), a2 @2MB+4KB (256KB),
//     phase-B Ahi @4MB (32MB), phase-B Alo @4MB+32MB
//   dist region D    = d_out[134,217,728 .. 402,653,184)
//     phase-A Ahi/Alo live in D's SECOND half while gemm-A writes D's first
//     half; gemm-B then overwrites D's second half (phase-A data dead).
//   K3 runs last and overwrites Q with the real quantized output.
// ---------------------------------------------------------------------------
extern "C" void kernel_launch(void* const* d_in, const int* in_sizes, int n_in,
                              void* d_out, int out_size, void* d_ws, size_t ws_size,
                              hipStream_t stream) {
    const float* x  = (const float*)d_in[0];
    const float* cb = (const float*)d_in[1];

    char* out = (char*)d_out;
    const size_t QBYTES = (size_t)NTOK * LD * 4;     // 134,217,728
    float* quant = (float*)out;
    float* dist  = (float*)(out + QBYTES);

    u16*   cbhi = (u16*)out;
    u16*   cblo = (u16*)(out + 1048576);
    float* b2   = (float*)(out + 2097152);
    float* a2   = (float*)(out + 2101248);
    u16*   A2hi = (u16*)(out + 4194304);
    u16*   A2lo = (u16*)(out + 4194304 + 33554432);

    char*  db   = out + QBYTES;
    u16*   A1hi = (u16*)(db + 134217728);
    u16*   A1lo = (u16*)(db + 134217728 + 33554432);

    // converters
    convert_rows_kernel<<<CB / 4, 256, 0, stream>>>(cb, cbhi, cblo, b2, CB);
    convert_rows_kernel<<<HALFM / 4, 256, 0, stream>>>(x, A1hi, A1lo, a2, HALFM);
    convert_rows_kernel<<<HALFM / 4, 256, 0, stream>>>(
        x + (size_t)HALFM * LD, A2hi, A2lo, a2 + HALFM, HALFM);

    // distance GEMMs (two M-phases)
    dim3 grid(CB / 128, HALFM / 128);
    mfma_dist_kernel<<<grid, 256, 0, stream>>>(A1hi, A1lo, cbhi, cblo,
                                               a2, b2, dist, 0);
    mfma_dist_kernel<<<grid, 256, 0, stream>>>(A2hi, A2lo, cbhi, cblo,
                                               a2, b2, dist, HALFM);

    // argmin + gather (overwrites scratch in Q with the real output)
    argmin_gather_kernel<<<NTOK / 4, 256, 0, stream>>>(dist, cb, quant);
}